// Round 4
// baseline (301.986 us; speedup 1.0000x reference)
//
#include <hip/hip_runtime.h>
#include <cmath>

#define TSX 32
#define HALO 5
#define XPAD 8        // staged halo per side (multiple of 4 for float4 masking)
#define NCOLS 42      // TSX + 2*HALO (columns vertical-blurred)
#define CHROWS 26     // 16 + 2*HALO  (input rows per 16-row chunk)
#define RSTR 48       // raw row stride (floats) = TSX + 2*XPAD
#define RF4 12        // float4s per raw row
#define VSTR 44       // vb row stride (floats), multiple of 4 for b128 alignment
#define WIDTH 512
#define HEIGHT 512

struct GW { float g[11]; };

__device__ __forceinline__ float ssim_term(float mu1, float mu2,
                                           float x2b, float y2b, float xyb)
{
    const float C1 = 1e-4f, C2 = 9e-4f;
    float mu12 = mu1 * mu2;
    float num  = (2.f * mu12 + C1) * (2.f * (xyb - mu12) + C2);
    float den  = (mu1 * mu1 + mu2 * mu2 + C1) *
                 ((x2b - mu1 * mu1) + (y2b - mu2 * mu2) + C2);
    return num / den;
}

__global__ __launch_bounds__(256, 4)
void ssim_tile(const float* __restrict__ fI, const float* __restrict__ aI,
               const float* __restrict__ bI, float* __restrict__ bsum,
               GW gw, int W, int H)
{
    __shared__ __align__(16) float raw[3][CHROWS * RSTR];   // 15.0 KB
    __shared__ __align__(16) float vb[8][16 * VSTR];        // 22.0 KB
    __shared__ float red[4];

    const int tid = threadIdx.x;
    const int bx = blockIdx.x;
    const int x0 = bx * TSX;
    const int y0 = blockIdx.y * 32;
    const size_t pbase = (size_t)blockIdx.z * (size_t)(W * H);
    const bool xl = (bx == 0);
    const bool xr = (bx == gridDim.x - 1);

    // phase-3 thread map: 16 rows x 8 four-col strips = 128 active threads.
    // b128-aligned window reads; idle lanes are covered by 4 blocks/CU.
    const int r3 = tid >> 3;          // 0..15 (for tid < 128)
    const int s3 = tid & 7;           // 0..7  : 4-col strip
    const bool p3act = (tid < 128);

    // phase-2 thread map: 42 cols x 4 row-quads = 168 tasks (single pass)
    const int j2  = tid % NCOLS;      // 0..41
    const int rg2 = tid / NCOLS;      // 0..6 ; active iff rg2 < 4
    const bool p2act = (rg2 < 4);

    float part = 0.f;

    for (int c = 0; c < 2; ++c) {
        if (c) __syncthreads();           // vb of chunk0 consumed before reuse
        const int yb = y0 + 16 * c - HALO;

        // ---- phase 1: global -> LDS raw (float4, whole-f4 edge masking) ----
        #pragma unroll
        for (int a = 0; a < 3; ++a) {
            const float* __restrict__ sp = (a == 0) ? fI : (a == 1) ? aI : bI;
            #pragma unroll 2
            for (int idx = tid; idx < CHROWS * RF4; idx += 256) {
                int r  = idx / RF4;
                int j4 = idx - r * RF4;
                int yy = yb + r;
                bool ok = ((unsigned)yy < (unsigned)H) &&
                          !(xl && j4 < 2) && !(xr && j4 >= 10);
                float4 v = make_float4(0.f, 0.f, 0.f, 0.f);
                if (ok)
                    v = *(const float4*)(sp + pbase + (size_t)yy * W +
                                         (x0 - XPAD + 4 * j4));
                *(float4*)(&raw[a][r * RSTR + 4 * j4]) = v;
            }
        }
        __syncthreads();

        // ---- phase 2: vertical blur of 8 fields into vb (16 rows) ----
        // task = (col j2, row-quad rg2): 4 output rows per task, k = 0..14
        if (p2act) {
            float acc[4][8];
            #pragma unroll
            for (int ri = 0; ri < 4; ++ri)
                #pragma unroll
                for (int q = 0; q < 8; ++q) acc[ri][q] = 0.f;
            #pragma unroll
            for (int k = 0; k < 15; ++k) {
                int i = 4 * rg2 + k;
                float a0 = raw[0][i * RSTR + XPAD - HALO + j2];
                float a1 = raw[1][i * RSTR + XPAD - HALO + j2];
                float a2 = raw[2][i * RSTR + XPAD - HALO + j2];
                float p[8];
                p[0] = a0; p[1] = a1; p[2] = a2;
                p[3] = a0 * a0; p[4] = a1 * a1; p[5] = a2 * a2;
                p[6] = a0 * a1; p[7] = a0 * a2;
                #pragma unroll
                for (int ri = 0; ri < 4; ++ri) {
                    if (k >= ri && k - ri <= 10) {
                        float w = gw.g[k - ri];
                        #pragma unroll
                        for (int q = 0; q < 8; ++q)
                            acc[ri][q] = fmaf(w, p[q], acc[ri][q]);
                    }
                }
            }
            #pragma unroll
            for (int ri = 0; ri < 4; ++ri) {
                int R = 4 * rg2 + ri;
                #pragma unroll
                for (int q = 0; q < 8; ++q)
                    vb[q][R * VSTR + j2] = acc[ri][q];
            }
        }
        __syncthreads();

        // ---- phase 3: horizontal blur (aligned b128 reads, static idx) + SSIM
        if (p3act) {
            float res[8][4];
            #pragma unroll
            for (int q = 0; q < 8; ++q) {
                const float4* vp = (const float4*)(&vb[q][r3 * VSTR + 4 * s3]);
                float4 w0 = vp[0], w1 = vp[1], w2 = vp[2], w3 = vp[3];
                float vr[16] = { w0.x, w0.y, w0.z, w0.w,  w1.x, w1.y, w1.z, w1.w,
                                 w2.x, w2.y, w2.z, w2.w,  w3.x, w3.y, w3.z, w3.w };
                #pragma unroll
                for (int jj = 0; jj < 4; ++jj) {
                    float acc = 0.f;
                    #pragma unroll
                    for (int t = 0; t < 11; ++t)
                        acc = fmaf(gw.g[t], vr[jj + t], acc);
                    res[q][jj] = acc;
                }
            }
            #pragma unroll
            for (int jj = 0; jj < 4; ++jj) {
                // fields: 0=F 1=A 2=B 3=F2 4=A2 5=B2 6=FA 7=FB
                part += ssim_term(res[0][jj], res[1][jj], res[3][jj], res[4][jj], res[6][jj]);
                part += ssim_term(res[0][jj], res[2][jj], res[3][jj], res[5][jj], res[7][jj]);
            }
        }
    }

    // ---- phase 4: block reduction -> per-block partial (no atomics) ----
    #pragma unroll
    for (int off = 32; off > 0; off >>= 1) part += __shfl_down(part, off);
    if ((tid & 63) == 0) red[tid >> 6] = part;
    __syncthreads();
    if (tid == 0) {
        int bid = blockIdx.x + gridDim.x * (blockIdx.y + gridDim.y * blockIdx.z);
        bsum[bid] = red[0] + red[1] + red[2] + red[3];
    }
}

__global__ __launch_bounds__(256)
void ssim_final(const float* __restrict__ bsum, float* __restrict__ out,
                int nb, float invTwoN)
{
    __shared__ float sred[4];
    float s = 0.f;
    for (int i = threadIdx.x; i < nb; i += 256) s += bsum[i];
    #pragma unroll
    for (int off = 32; off > 0; off >>= 1) s += __shfl_down(s, off);
    if ((threadIdx.x & 63) == 0) sred[threadIdx.x >> 6] = s;
    __syncthreads();
    if (threadIdx.x == 0)
        out[0] = 1.f - (sred[0] + sred[1] + sred[2] + sred[3]) * invTwoN;
}

extern "C" void kernel_launch(void* const* d_in, const int* in_sizes, int n_in,
                              void* d_out, int out_size, void* d_ws, size_t ws_size,
                              hipStream_t stream)
{
    const float* f  = (const float*)d_in[0];
    const float* s1 = (const float*)d_in[1];
    const float* s2 = (const float*)d_in[2];
    float* out  = (float*)d_out;
    float* bsum = (float*)d_ws;         // 12288 floats = 48 KB of scratch

    const int W = WIDTH, H = HEIGHT;
    const int N = in_sizes[0];          // 48 * 512 * 512
    const int planes = N / (W * H);

    GW gw;
    double gd[11], gs = 0.0;
    for (int i = 0; i < 11; ++i) {
        double d = (double)(i - 5);
        gd[i] = exp(-(d * d) / 4.5);    // 2*sigma^2 = 4.5
        gs += gd[i];
    }
    for (int i = 0; i < 11; ++i) gw.g[i] = (float)(gd[i] / gs);

    dim3 grid(W / TSX, H / 32, planes);
    const int nb = (W / TSX) * (H / 32) * planes;
    ssim_tile<<<grid, dim3(256), 0, stream>>>(f, s1, s2, bsum, gw, W, H);
    ssim_final<<<1, dim3(256), 0, stream>>>(bsum, out, nb, 0.5f / (float)N);
}

// Round 5
// 265.460 us; speedup vs baseline: 1.1376x; 1.1376x over previous
//
#include <hip/hip_runtime.h>
#include <cmath>

#define HALO 5
#define TSX 32
#define CH 16            // output rows per chunk
#define CHR 26           // input rows per chunk = CH + 2*HALO
#define HSTR 36          // hb col stride (floats): 32 + pad, multiple of 4
#define WIDTH 512
#define HEIGHT 512

struct GW { float g[11]; };

__device__ __forceinline__ float ssim_term(float mu1, float mu2,
                                           float x2b, float y2b, float xyb)
{
    const float C1 = 1e-4f, C2 = 9e-4f;
    float mu12 = mu1 * mu2;
    float num  = (2.f * mu12 + C1) * (2.f * (xyb - mu12) + C2);
    float den  = (mu1 * mu1 + mu2 * mu2 + C1) *
                 ((x2b - mu1 * mu1) + (y2b - mu2 * mu2) + C2);
    return num / den;
}

__global__ __launch_bounds__(256, 5)
void ssim_tile(const float* __restrict__ fI, const float* __restrict__ aI,
               const float* __restrict__ bI, float* __restrict__ bsum,
               GW gw)
{
    // hb[q][i][j]: horizontally-blurred field q, input row i, out col j
    __shared__ __align__(16) float hb[8][CHR * HSTR];      // 29.25 KB
    __shared__ float red[4];

    const int tid = threadIdx.x;
    const int x0 = blockIdx.x * TSX;
    const int y0 = blockIdx.y * 32;
    const size_t pbase = (size_t)blockIdx.z * (size_t)(WIDTH * HEIGHT);

    // ---- phase A map: 26 rows x 8 col-quads = 208 active ----
    const int rA = tid >> 3;          // 0..31 (active < 26)
    const int qA = tid & 7;           // quad -> out cols 4qA..4qA+3
    const bool actA = (rA < CHR);
    const int gx0 = x0 + 4 * qA - 8;  // first loaded global col (5 quads)

    // ---- phase B map: 32 cols x 4 row-quads = 128 active ----
    const int jB  = tid & 31;
    const int rgB = tid >> 5;         // 0..7 (active < 4)
    const bool actB = (rgB < 4);

    float part = 0.f;

    for (int c = 0; c < 2; ++c) {
        if (c) __syncthreads();            // prev chunk's phase B done
        const int yb = y0 + CH * c - HALO;

        // ---- phase A: global -> registers -> horiz blur -> hb ----
        if (actA) {
            const int yy = yb + rA;
            const bool yok = (unsigned)yy < (unsigned)HEIGHT;
            const float* rowf = fI + pbase + (size_t)yy * WIDTH;
            const float* rowa = aI + pbase + (size_t)yy * WIDTH;
            const float* rowb = bI + pbase + (size_t)yy * WIDTH;

            float acc[4][8];
            #pragma unroll
            for (int jj = 0; jj < 4; ++jj)
                #pragma unroll
                for (int q = 0; q < 8; ++q) acc[jj][q] = 0.f;

            #pragma unroll
            for (int k = 0; k < 5; ++k) {
                const int g = gx0 + 4 * k;
                const bool ok = yok && (g >= 0) && (g <= WIDTH - 4);
                float4 vf = ok ? *(const float4*)(rowf + g) : make_float4(0,0,0,0);
                float4 va = ok ? *(const float4*)(rowa + g) : make_float4(0,0,0,0);
                float4 vb = ok ? *(const float4*)(rowb + g) : make_float4(0,0,0,0);
                const float fs[4] = { vf.x, vf.y, vf.z, vf.w };
                const float as[4] = { va.x, va.y, va.z, va.w };
                const float bs[4] = { vb.x, vb.y, vb.z, vb.w };
                #pragma unroll
                for (int cc = 0; cc < 4; ++cc) {
                    const int t = 4 * k + cc - 3;     // window col 0..13
                    if (t < 0 || t > 13) continue;    // static prune
                    const float f = fs[cc], a = as[cc], b = bs[cc];
                    float p[8];
                    p[0] = f; p[1] = a; p[2] = b;
                    p[3] = f * f; p[4] = a * a; p[5] = b * b;
                    p[6] = f * a; p[7] = f * b;
                    #pragma unroll
                    for (int jj = 0; jj < 4; ++jj) {
                        const int u = t - jj;         // tap index
                        if (u >= 0 && u <= 10) {
                            const float w = gw.g[u];
                            #pragma unroll
                            for (int q = 0; q < 8; ++q)
                                acc[jj][q] = fmaf(w, p[q], acc[jj][q]);
                        }
                    }
                }
            }
            // b128 write per field: cols 4qA..4qA+3 of row rA
            #pragma unroll
            for (int q = 0; q < 8; ++q) {
                *(float4*)(&hb[q][rA * HSTR + 4 * qA]) =
                    make_float4(acc[0][q], acc[1][q], acc[2][q], acc[3][q]);
            }
        }
        __syncthreads();

        // ---- phase B: vertical blur from hb (conflict-free b32) + SSIM ----
        if (actB) {
            const int R = 4 * rgB;                    // chunk-local out rows R..R+3
            float acc2[4][8];
            #pragma unroll
            for (int ri = 0; ri < 4; ++ri)
                #pragma unroll
                for (int q = 0; q < 8; ++q) acc2[ri][q] = 0.f;
            #pragma unroll
            for (int k = 0; k < 14; ++k) {
                float hv[8];
                #pragma unroll
                for (int q = 0; q < 8; ++q)
                    hv[q] = hb[q][(R + k) * HSTR + jB];
                #pragma unroll
                for (int ri = 0; ri < 4; ++ri) {
                    const int u = k - ri;
                    if (u >= 0 && u <= 10) {
                        const float w = gw.g[u];
                        #pragma unroll
                        for (int q = 0; q < 8; ++q)
                            acc2[ri][q] = fmaf(w, hv[q], acc2[ri][q]);
                    }
                }
            }
            #pragma unroll
            for (int ri = 0; ri < 4; ++ri) {
                // fields: 0=F 1=A 2=B 3=F2 4=A2 5=B2 6=FA 7=FB
                part += ssim_term(acc2[ri][0], acc2[ri][1],
                                  acc2[ri][3], acc2[ri][4], acc2[ri][6]);
                part += ssim_term(acc2[ri][0], acc2[ri][2],
                                  acc2[ri][3], acc2[ri][5], acc2[ri][7]);
            }
        }
    }

    // ---- reduction -> per-block partial (no atomics) ----
    #pragma unroll
    for (int off = 32; off > 0; off >>= 1) part += __shfl_down(part, off);
    if ((tid & 63) == 0) red[tid >> 6] = part;
    __syncthreads();
    if (tid == 0) {
        int bid = blockIdx.x + gridDim.x * (blockIdx.y + gridDim.y * blockIdx.z);
        bsum[bid] = red[0] + red[1] + red[2] + red[3];
    }
}

__global__ __launch_bounds__(256)
void ssim_final(const float* __restrict__ bsum, float* __restrict__ out,
                int nb, float invTwoN)
{
    __shared__ float sred[4];
    float s = 0.f;
    for (int i = threadIdx.x; i < nb; i += 256) s += bsum[i];
    #pragma unroll
    for (int off = 32; off > 0; off >>= 1) s += __shfl_down(s, off);
    if ((threadIdx.x & 63) == 0) sred[threadIdx.x >> 6] = s;
    __syncthreads();
    if (threadIdx.x == 0)
        out[0] = 1.f - (sred[0] + sred[1] + sred[2] + sred[3]) * invTwoN;
}

extern "C" void kernel_launch(void* const* d_in, const int* in_sizes, int n_in,
                              void* d_out, int out_size, void* d_ws, size_t ws_size,
                              hipStream_t stream)
{
    const float* f  = (const float*)d_in[0];
    const float* s1 = (const float*)d_in[1];
    const float* s2 = (const float*)d_in[2];
    float* out  = (float*)d_out;
    float* bsum = (float*)d_ws;          // 12288 floats = 48 KB scratch

    const int N = in_sizes[0];           // 48 * 512 * 512
    const int planes = N / (WIDTH * HEIGHT);

    GW gw;
    double gd[11], gs = 0.0;
    for (int i = 0; i < 11; ++i) {
        double d = (double)(i - 5);
        gd[i] = exp(-(d * d) / 4.5);     // 2*sigma^2 = 4.5
        gs += gd[i];
    }
    for (int i = 0; i < 11; ++i) gw.g[i] = (float)(gd[i] / gs);

    dim3 grid(WIDTH / TSX, HEIGHT / 32, planes);
    const int nb = (WIDTH / TSX) * (HEIGHT / 32) * planes;
    ssim_tile<<<grid, dim3(256), 0, stream>>>(f, s1, s2, bsum, gw);
    ssim_final<<<1, dim3(256), 0, stream>>>(bsum, out, nb, 0.5f / (float)N);
}